// Round 12
// baseline (236.505 us; speedup 1.0000x reference)
//
#include <hip/hip_runtime.h>

#define N_ATOMS 20000
#define N_EDGES 80000
#define ATOM_DIM 29
#define BOND_DIM 11
#define UNITS 64
#define STEPS 4
#define GCOLS 768      // 12*64 (11 bond slices + 1 plain-sum slice)
#define KTOT  832      // 768 (G) + 64 (h)
#define BM    32       // atoms per block; 625 * 32 = 20000 exactly
#define NTH   256      // 4 waves
#define ASTRIDE 836    // f16 row stride of A-tile (53,504 B -> 3 blocks/CU)
#define CT_MAIN 12     // main col-tiles (N=192: z,r,xh)
#define KT_MAIN 26     // K=832
#define CT_RH 4        // rh col-tiles (N=64)
#define KT_RH 2        // K=64 (h only)
#define GSTRIDE 193    // gates f32 row stride (overlay in As)
#define RSTRIDE 65     // rh f32 row stride (overlay in As)

typedef _Float16 f16;
typedef __attribute__((ext_vector_type(8))) _Float16 f16x8;
typedef __attribute__((ext_vector_type(4))) float f32x4;

__global__ void init_h(const float* __restrict__ atom, float* __restrict__ h,
                       f16* __restrict__ h16) {
    int idx = blockIdx.x*256 + threadIdx.x;
    if (idx >= N_ATOMS*UNITS) return;
    int a = idx >> 6, i = idx & 63;
    float v = (i < ATOM_DIM) ? atom[a*ATOM_DIM + i] : 0.f;
    h[idx] = v;
    h16[idx] = (f16)v;
}

// row_ptr[a] = first edge index with src >= a (edges sorted by src)
__global__ void build_rowptr(const int* __restrict__ pair, int* __restrict__ row_ptr) {
    int e = blockIdx.x*256 + threadIdx.x;
    if (e >= N_EDGES) return;
    int s = pair[2*e];
    if (e == 0) for (int a = 0; a <= s; a++) row_ptr[a] = 0;
    int snext = (e == N_EDGES-1) ? N_ATOMS : pair[2*(e+1)];
    for (int a = s+1; a <= snext; a++) row_ptr[a] = e+1;
}

// W3m: tile-major [ct][kt][lane][8] f16; tile (ct,kt) holds B-frag for
// cols ct*16+lr (0..191 = z|r|xh), k = kt*32+lq*8+e. One wave-load = 1KB contig.
// col comp: 0=zsum 1=rsum 2=xh. k<768: (EKT2 @ gk_comp); k>=768: grk (comp<2) else 0.
// Also writes bias2[256] = [bz|br|bxh|brh].
__global__ void build_w3m(const float* __restrict__ ek, const float* __restrict__ eb,
                          const float* __restrict__ gk, const float* __restrict__ grk,
                          const float* __restrict__ gb, f16* __restrict__ W3m,
                          float* __restrict__ bias2) {
    int idx = blockIdx.x*256 + threadIdx.x;
    if (idx < 256) {
        int comp = idx >> 6, i = idx & 63;
        float b;
        if (comp == 0)      b = gb[i]       + gb[192 + i];
        else if (comp == 1) b = gb[64 + i]  + gb[256 + i];
        else if (comp == 2) b = gb[128 + i];
        else                b = gb[320 + i];
        bias2[idx] = b;
    }
    if (idx >= CT_MAIN*KT_MAIN*512) return;
    int t = idx >> 9, rem = idx & 511;
    int ct = t / KT_MAIN, kt = t % KT_MAIN;
    int lane = rem >> 3, e = rem & 7;
    int lq = lane >> 4, lr = lane & 15;
    int col = ct*16 + lr;           // 0..191
    int comp = col >> 6, i = col & 63;
    int k = kt*32 + lq*8 + e;       // 0..831
    float val = 0.f;
    if (k < GCOLS) {
        int b = k >> 6, q = k & 63;
        const float* E = (b < BOND_DIM) ? (ek + (size_t)b*4096 + q) : (eb + q);
        const float* T = gk + comp*64 + i;
        #pragma unroll 8
        for (int m = 0; m < 64; m++) val += E[m*64] * T[m*192];
    } else {
        int j = k - GCOLS;
        if (comp < 2) val = grk[j*192 + comp*64 + i];
        // comp==2 (xh): zero h-part
    }
    W3m[idx] = (f16)val;
}

// W3r: tile-major [rt][kt][lane][8]; cols i = rt*16+lr, k = j = kt*32+lq*8+e (h rows).
__global__ void build_w3r(const float* __restrict__ grk, f16* __restrict__ W3r) {
    int idx = blockIdx.x*256 + threadIdx.x;
    if (idx >= CT_RH*KT_RH*512) return;
    int t = idx >> 9, rem = idx & 511;
    int rt = t / KT_RH, kt = t % KT_RH;
    int lane = rem >> 3, e = rem & 7;
    int lq = lane >> 4, lr = lane & 15;
    int i = rt*16 + lr;
    int j = kt*32 + lq*8 + e;
    W3r[idx] = (f16)grk[j*192 + 128 + i];
}

// One fused step per 32-atom block (grid=625, 4 waves, 3 blocks/CU):
//  phase 0: issue depth-2 B prefetch (latency hides under gather)
//  phase 1: gather -> A-tile [G | h] (32 x 832 f16) in LDS; wave owns 8 atoms
//  phase 1b: prefetch epilogue operands (h rows, biases)
//  phase 2: waves 0-2: main GEMM (4 col-tiles x 2 row-tiles each — every B frag
//           feeds 2 MFMAs); wave 3: rh GEMM (K=64, 2 row-tiles)
//  phase 3: acc -> LDS overlay, recombine, GRU epilogue -> h, h16_out
__global__ __launch_bounds__(NTH, 3) void fused_step(
    const int* __restrict__ pair, const int* __restrict__ row_ptr,
    const float* __restrict__ bond, const f16* __restrict__ h16_in,
    f16* __restrict__ h16_out, const f16* __restrict__ W3m,
    const f16* __restrict__ W3r, const float* __restrict__ bias2,
    float* __restrict__ h) {
  __shared__ __align__(16) char smem[BM*ASTRIDE*2];          // 53,504 B
  f16 (*As)[ASTRIDE] = (f16 (*)[ASTRIDE])smem;
  float (*gates)[GSTRIDE] = (float (*)[GSTRIDE])smem;        // 24,704 B (overlay)
  float (*rhb)[RSTRIDE] = (float (*)[RSTRIDE])(smem + BM*GSTRIDE*4); // 8,320 B

  int a0 = blockIdx.x * BM;
  int tid = threadIdx.x;
  int lane = tid & 63, w = tid >> 6;
  int lq = lane >> 4, lr = lane & 15;

  // ---------- phase 0: B prefetch (depth 2 per stream), issued before gather
  const f16* bp[4];
  if (w < 3) {
    #pragma unroll
    for (int n=0;n<4;n++)
      bp[n] = W3m + ((size_t)(w*4 + n)*KT_MAIN)*512 + lane*8;
  } else {
    #pragma unroll
    for (int n=0;n<4;n++)
      bp[n] = W3r + ((size_t)n*KT_RH)*512 + lane*8;
  }
  f16x8 pb[4][2];
  #pragma unroll
  for (int n=0;n<4;n++) {
    pb[n][0] = *(const f16x8*)(bp[n]);
    pb[n][1] = *(const f16x8*)(bp[n] + 512);
  }

  // ---------- phase 1: gather; wave w owns atoms w*8 .. w*8+7, lane = h-col
  for (int t = 0; t < 8; t++) {
    int r = w*8 + t;
    int a = a0 + r;
    int s = row_ptr[a], e_end = row_ptr[a+1];
    float g[BOND_DIM+1];
    #pragma unroll
    for (int b=0;b<=BOND_DIM;b++) g[b] = 0.f;
    int e = s;
    for (; e + 1 < e_end; e += 2) {
      int d0 = pair[2*e+1], d1 = pair[2*e+3];
      float h0 = (float)h16_in[(size_t)d0*UNITS + lane];
      float h1 = (float)h16_in[(size_t)d1*UNITS + lane];
      g[BOND_DIM] += h0 + h1;
      #pragma unroll
      for (int b=0;b<BOND_DIM;b++)
        g[b] += bond[(size_t)e*BOND_DIM + b]*h0 + bond[(size_t)(e+1)*BOND_DIM + b]*h1;
    }
    if (e < e_end) {
      int d0 = pair[2*e+1];
      float h0 = (float)h16_in[(size_t)d0*UNITS + lane];
      g[BOND_DIM] += h0;
      #pragma unroll
      for (int b=0;b<BOND_DIM;b++) g[b] += bond[(size_t)e*BOND_DIM + b]*h0;
    }
    #pragma unroll
    for (int b=0;b<=BOND_DIM;b++) As[r][b*64 + lane] = (f16)g[b];
    As[r][GCOLS + lane] = h16_in[(size_t)a*UNITS + lane];
  }

  // ---------- phase 1b: prefetch epilogue operands (independent of GEMM)
  int ei = tid & 63;
  float bz  = bias2[ei];
  float br  = bias2[64 + ei];
  float bxh = bias2[128 + ei];
  float brh = bias2[192 + ei];
  float hold[8];
  #pragma unroll
  for (int p=0;p<8;p++)
    hold[p] = h[(size_t)(a0 + (tid >> 6) + p*4)*UNITS + ei];

  __syncthreads();

  // ---------- phase 2: GEMM, rolling register double-buffer on B; 2 row-tiles
  f32x4 acc[2][4];
  #pragma unroll
  for (int m=0;m<2;m++)
    #pragma unroll
    for (int n=0;n<4;n++) acc[m][n] = (f32x4){0.f,0.f,0.f,0.f};

  if (w < 3) {
    #pragma unroll 2
    for (int kt = 0; kt < KT_MAIN; kt++) {
      f16x8 af0 = *(const f16x8*)&As[lr][kt*32 + lq*8];
      f16x8 af1 = *(const f16x8*)&As[16 + lr][kt*32 + lq*8];
      #pragma unroll
      for (int n=0;n<4;n++) {
        acc[0][n] = __builtin_amdgcn_mfma_f32_16x16x32_f16(af0, pb[n][kt&1], acc[0][n], 0, 0, 0);
        acc[1][n] = __builtin_amdgcn_mfma_f32_16x16x32_f16(af1, pb[n][kt&1], acc[1][n], 0, 0, 0);
      }
      if (kt + 2 < KT_MAIN) {
        #pragma unroll
        for (int n=0;n<4;n++)
          pb[n][kt&1] = *(const f16x8*)(bp[n] + (size_t)(kt+2)*512);
      }
    }
  } else {
    #pragma unroll
    for (int kt = 0; kt < KT_RH; kt++) {
      f16x8 af0 = *(const f16x8*)&As[lr][GCOLS + kt*32 + lq*8];
      f16x8 af1 = *(const f16x8*)&As[16 + lr][GCOLS + kt*32 + lq*8];
      #pragma unroll
      for (int n=0;n<4;n++) {
        acc[0][n] = __builtin_amdgcn_mfma_f32_16x16x32_f16(af0, pb[n][kt], acc[0][n], 0, 0, 0);
        acc[1][n] = __builtin_amdgcn_mfma_f32_16x16x32_f16(af1, pb[n][kt], acc[1][n], 0, 0, 0);
      }
    }
  }
  __syncthreads();   // all As reads complete before overwrite

  // ---------- phase 3a: acc -> LDS (C/D layout: col=lane&15, row=lq*4+rr)
  if (w < 3) {
    #pragma unroll
    for (int m=0;m<2;m++)
      #pragma unroll
      for (int n=0;n<4;n++) {
        int col = (w*4+n)*16 + lr;
        #pragma unroll
        for (int rr=0;rr<4;rr++)
          gates[m*16 + lq*4 + rr][col] = acc[m][n][rr];
      }
  } else {
    #pragma unroll
    for (int m=0;m<2;m++)
      #pragma unroll
      for (int n=0;n<4;n++) {
        int col = n*16 + lr;
        #pragma unroll
        for (int rr=0;rr<4;rr++)
          rhb[m*16 + lq*4 + rr][col] = acc[m][n][rr];
      }
  }
  __syncthreads();

  // ---------- phase 3b: GRU epilogue; thread -> (a_loc = tid>>6 + p*4, i = tid&63)
  #pragma unroll
  for (int p=0;p<8;p++) {
    int a_loc = (tid >> 6) + p*4;
    int a = a0 + a_loc;
    float zs = gates[a_loc][ei]        + bz;
    float rs = gates[a_loc][64 + ei]   + br;
    float xh = gates[a_loc][128 + ei]  + bxh;
    float rh = rhb[a_loc][ei]          + brh;
    float z  = 1.f/(1.f + __expf(-zs));
    float rg = 1.f/(1.f + __expf(-rs));
    float hh = tanhf(xh + rg*rh);
    float hn = z*hold[p] + (1.f - z)*hh;
    h[(size_t)a*UNITS + ei] = hn;
    h16_out[(size_t)a*UNITS + ei] = (f16)hn;
  }
}

extern "C" void kernel_launch(void* const* d_in, const int* in_sizes, int n_in,
                              void* d_out, int out_size, void* d_ws, size_t ws_size,
                              hipStream_t stream) {
  const float* atom  = (const float*)d_in[0];
  const float* bond  = (const float*)d_in[1];
  const int*   pair  = (const int*)d_in[2];
  const float* ek    = (const float*)d_in[3];
  const float* eb    = (const float*)d_in[4];
  const float* gk    = (const float*)d_in[5];
  const float* grk   = (const float*)d_in[6];
  const float* gbias = (const float*)d_in[7];

  float* h = (float*)d_out;                          // 20000x64 fp32

  char* w = (char*)d_ws;
  int*   row_ptr = (int*)w;        w += 80032;                          // 20004 ints
  f16*   h16a    = (f16*)w;        w += (size_t)N_ATOMS*UNITS*2;
  f16*   h16b    = (f16*)w;        w += (size_t)N_ATOMS*UNITS*2;
  f16*   W3m     = (f16*)w;        w += (size_t)CT_MAIN*KT_MAIN*512*2;  // 319,488 B
  f16*   W3r     = (f16*)w;        w += (size_t)CT_RH*KT_RH*512*2;      // 8,192 B
  float* bias2   = (float*)w;      w += (size_t)256*4;

  init_h<<<(N_ATOMS*UNITS+255)/256, 256, 0, stream>>>(atom, h, h16a);
  build_rowptr<<<(N_EDGES+255)/256, 256, 0, stream>>>(pair, row_ptr);
  build_w3m<<<(CT_MAIN*KT_MAIN*512+255)/256, 256, 0, stream>>>(ek, eb, gk, grk, gbias, W3m, bias2);
  build_w3r<<<(CT_RH*KT_RH*512+255)/256, 256, 0, stream>>>(grk, W3r);

  f16* bufs[2] = { h16a, h16b };
  for (int s=0; s<STEPS; s++) {
    fused_step<<<N_ATOMS/BM, NTH, 0, stream>>>(
        pair, row_ptr, bond, bufs[s & 1], bufs[(s+1) & 1], W3m, W3r, bias2, h);
  }
}